// Round 3
// baseline (141.721 us; speedup 1.0000x reference)
//
#include <hip/hip_runtime.h>
#include <cstdint>
#include <cstddef>

// Problem constants
#define FF 64
#define EE 64
#define HH 8
#define PP 512
#define MM 16384   // B*T = 64*256
#define KK 1024    // 2 * F * H  (both branches concatenated)

typedef __bf16 bf16x8 __attribute__((ext_vector_type(8)));
typedef float  floatx4 __attribute__((ext_vector_type(4)));

// float -> bf16 (RNE)
__device__ __forceinline__ unsigned short f2bf(float f) {
    unsigned int u = __float_as_uint(f);
    u += 0x7FFFu + ((u >> 16) & 1u);
    return (unsigned short)(u >> 16);
}

__device__ __forceinline__ unsigned pack2(unsigned short a, unsigned short b) {
    return (unsigned)a | ((unsigned)b << 16);
}

// fast tanh: 1 - 2/(exp2(2x*log2e)+1); err ~1e-6, far below bf16 quantization.
__device__ __forceinline__ float fast_tanh(float x) {
    float e, r;
    asm("v_exp_f32 %0, %1" : "=v"(e) : "v"(x * 2.8853900817779268f));
    float d = e + 1.0f;
    asm("v_rcp_f32 %0, %1" : "=v"(r) : "v"(d));
    return __builtin_fmaf(-2.0f, r, 1.0f);
}

// async global->LDS, 16B per lane; LDS dest = wave-uniform base + lane*16
__device__ __forceinline__ void gl_lds16(const unsigned short* g, unsigned short* s) {
    __builtin_amdgcn_global_load_lds(
        (__attribute__((address_space(1))) void*)(void*)g,
        (__attribute__((address_space(3))) void*)s,
        16, 0, 0);
}

// ---------------------------------------------------------------------------
// Phase 1: BmatT[n][k] (bf16, k-contiguous), k = br*512 + f*8 + h
//   BmatT[n][br,f,h] = sum_e w2[f,h,e] * W[(f*64+e)*512 + n]
// block = (br, f, n-half); thread owns one n column.  ~21 MB read -> ~4 us.
// ---------------------------------------------------------------------------
__global__ __launch_bounds__(256) void combine_kernel(
    const float* __restrict__ w2v, const float* __restrict__ w2t,
    const float* __restrict__ wx,  const float* __restrict__ wt,
    unsigned short* __restrict__ BmatT)
{
    const int tid = threadIdx.x;
    const int bid = blockIdx.x;
    const int br = bid >> 7;
    const int f  = (bid >> 1) & 63;
    const int nh = bid & 1;
    const float* __restrict__ w2 = br ? w2t : w2v;   // [F][H][E]
    const float* __restrict__ W  = br ? wt  : wx;    // [F*E][P]
    __shared__ float w2s[HH * EE];
    for (int i = tid; i < HH * EE; i += 256) w2s[i] = w2[f * HH * EE + i];
    __syncthreads();
    const int n = nh * 256 + tid;
    float acc[HH] = {0,0,0,0,0,0,0,0};
    const float* Wcol = W + (size_t)f * EE * PP + n;
    #pragma unroll 8
    for (int e = 0; e < EE; ++e) {
        const float wv = Wcol[(size_t)e * PP];
        #pragma unroll
        for (int h = 0; h < HH; ++h)
            acc[h] = __builtin_fmaf(w2s[h * EE + e], wv, acc[h]);
    }
    uint4 v;
    v.x = pack2(f2bf(acc[0]), f2bf(acc[1]));
    v.y = pack2(f2bf(acc[2]), f2bf(acc[3]));
    v.z = pack2(f2bf(acc[4]), f2bf(acc[5]));
    v.w = pack2(f2bf(acc[6]), f2bf(acc[7]));
    *reinterpret_cast<uint4*>(&BmatT[(size_t)n * KK + br * 512 + f * 8]) = v;
}

// ---------------------------------------------------------------------------
// Phase 2: fused featurize + GEMM.
//   out[m][n] = sum_k A[m][k]*BmatT[n][k] + bx[n] + bt[n]
//   A[m][br*512+f*8+h] = tanh(in_br[m][f]*w1[f][h]+b1[f][h])  computed IN-TILE
//     (eliminates the 67 MB Hc round-trip through HBM).
// 128x128 tile, BK=64, 4 waves each a 64x64 quadrant of 4x4 16x16x32 MFMAs.
// LDS convention (both As and Bs): row r's logical 16B chunk c lives at
// physical chunk c^(r&7).
//   - Bs staged via global_load_lds (global k-offset permuted per lane).
//   - As computed: thread (fi=tid&7, g=tid>>3) does rows r=g+32j, f=f0+fi;
//     writes 16B chunks; the 64 lanes of a wave cover all 32 banks uniformly
//     (8 words/bank = the b128 minimum) -> conflict-free.
//   - frag reads: physical chunk cl^(row&7), uniform 2 lanes/bank -> free.
// grid.x = m-tiles, grid.y = n-tiles: n-tiles of one m-stripe land on the
// same XCD (ids congruent mod 8) -> x/time re-reads served from L2.
// ---------------------------------------------------------------------------
__global__ __launch_bounds__(256) void gemm_fused_kernel(
    const float* __restrict__ x,   const float* __restrict__ tmv,
    const float* __restrict__ w1v, const float* __restrict__ b1v,
    const float* __restrict__ w1t, const float* __restrict__ b1t,
    const unsigned short* __restrict__ Bt,  // BmatT [PP][KK]
    const float* __restrict__ bx, const float* __restrict__ bt,
    float* __restrict__ out)                 // [MM][PP]
{
    __shared__ __align__(16) unsigned short As[128 * 64];  // 16 KB
    __shared__ __align__(16) unsigned short Bs[128 * 64];  // 16 KB
    __shared__ __align__(16) float w1s[2 * FF * HH];       // 4 KB [br][f][h]
    __shared__ __align__(16) float b1s[2 * FF * HH];       // 4 KB

    const int tid  = threadIdx.x;
    const int wave = tid >> 6;
    const int lane = tid & 63;
    const int m0 = blockIdx.x * 128;
    const int n0 = blockIdx.y * 128;

    // stage w1/b1 (512 float4s total: 256 w1 + 256 b1; tid covers one each)
    {
        const float4 wsrc = (tid < 128) ? reinterpret_cast<const float4*>(w1v)[tid]
                                        : reinterpret_cast<const float4*>(w1t)[tid - 128];
        const float4 bsrc = (tid < 128) ? reinterpret_cast<const float4*>(b1v)[tid]
                                        : reinterpret_cast<const float4*>(b1t)[tid - 128];
        reinterpret_cast<float4*>(w1s)[tid] = wsrc;
        reinterpret_cast<float4*>(b1s)[tid] = bsrc;
    }
    __syncthreads();

    const int wr = wave >> 1;
    const int wc = wave & 1;
    const int q   = lane >> 4;
    const int ml  = lane & 15;
    const int mlx = ml & 7;
    const int lr  = lane >> 3;             // 0..7 row within 8-row segment
    const int lkg = ((lane & 7) ^ lr) * 8; // swizzled global k-offset (shorts)
    const int fi  = tid & 7;               // feature sub-index for A-compute
    const int g   = tid >> 3;              // 0..31: base row group

    floatx4 acc[4][4];
    #pragma unroll
    for (int i = 0; i < 4; ++i)
        #pragma unroll
        for (int j = 0; j < 4; ++j)
            acc[i][j] = (floatx4){0.f, 0.f, 0.f, 0.f};

    for (int k0 = 0; k0 < KK; k0 += 64) {
        const int br = k0 >> 9;
        const int f0 = (k0 >> 3) & 63;

        // ---- B staging first (DMA overlaps the tanh VALU below) ----
        #pragma unroll
        for (int i = 0; i < 4; ++i) {
            const int seg = wave * 4 + i;
            gl_lds16(&Bt[(size_t)(n0 + seg * 8 + lr) * KK + k0 + lkg], &Bs[seg * 512]);
        }

        // ---- A tile compute: rows g+32j, f = f0+fi, 8 h values each ----
        {
            const float* __restrict__ inp = br ? tmv : x;
            const int f = f0 + fi;
            const float4 wlo = reinterpret_cast<const float4*>(w1s)[br * 128 + f * 2];
            const float4 whi = reinterpret_cast<const float4*>(w1s)[br * 128 + f * 2 + 1];
            const float4 blo = reinterpret_cast<const float4*>(b1s)[br * 128 + f * 2];
            const float4 bhi = reinterpret_cast<const float4*>(b1s)[br * 128 + f * 2 + 1];
            float vals[4];
            #pragma unroll
            for (int j = 0; j < 4; ++j)
                vals[j] = inp[(size_t)(m0 + g + 32 * j) * FF + f];
            const int pchunk = (fi ^ (g & 7)) * 8;   // physical chunk offset (shorts)
            #pragma unroll
            for (int j = 0; j < 4; ++j) {
                const int r = g + 32 * j;
                const float val = vals[j];
                float hv[8];
                hv[0] = fast_tanh(__builtin_fmaf(val, wlo.x, blo.x));
                hv[1] = fast_tanh(__builtin_fmaf(val, wlo.y, blo.y));
                hv[2] = fast_tanh(__builtin_fmaf(val, wlo.z, blo.z));
                hv[3] = fast_tanh(__builtin_fmaf(val, wlo.w, blo.w));
                hv[4] = fast_tanh(__builtin_fmaf(val, whi.x, bhi.x));
                hv[5] = fast_tanh(__builtin_fmaf(val, whi.y, bhi.y));
                hv[6] = fast_tanh(__builtin_fmaf(val, whi.z, bhi.z));
                hv[7] = fast_tanh(__builtin_fmaf(val, whi.w, bhi.w));
                uint4 v;
                v.x = pack2(f2bf(hv[0]), f2bf(hv[1]));
                v.y = pack2(f2bf(hv[2]), f2bf(hv[3]));
                v.z = pack2(f2bf(hv[4]), f2bf(hv[5]));
                v.w = pack2(f2bf(hv[6]), f2bf(hv[7]));
                *reinterpret_cast<uint4*>(&As[r * 64 + pchunk]) = v;
            }
        }
        __syncthreads();   // As writes + Bs DMA visible to all waves

        #pragma unroll
        for (int kk = 0; kk < 64; kk += 32) {
            const int cl = (kk >> 3) + q;          // logical chunk 0..7
            const int co = (cl ^ mlx) * 8;          // swizzled offset (shorts)
            bf16x8 af[4], bfr[4];
            #pragma unroll
            for (int mt = 0; mt < 4; ++mt)
                af[mt] = *reinterpret_cast<const bf16x8*>(
                    &As[(wr * 64 + mt * 16 + ml) * 64 + co]);
            #pragma unroll
            for (int nt = 0; nt < 4; ++nt)
                bfr[nt] = *reinterpret_cast<const bf16x8*>(
                    &Bs[(wc * 64 + nt * 16 + ml) * 64 + co]);
            #pragma unroll
            for (int mt = 0; mt < 4; ++mt)
                #pragma unroll
                for (int nt = 0; nt < 4; ++nt)
                    acc[mt][nt] = __builtin_amdgcn_mfma_f32_16x16x32_bf16(
                        af[mt], bfr[nt], acc[mt][nt], 0, 0, 0);
        }
        __syncthreads();   // before next iteration overwrites LDS
    }

    #pragma unroll
    for (int nt = 0; nt < 4; ++nt) {
        const int n = n0 + wc * 64 + nt * 16 + ml;
        const float bias = bx[n] + bt[n];
        #pragma unroll
        for (int mt = 0; mt < 4; ++mt) {
            const int mb = m0 + wr * 64 + mt * 16 + q * 4;
            #pragma unroll
            for (int r = 0; r < 4; ++r)
                out[(size_t)(mb + r) * PP + n] = acc[mt][nt][r] + bias;
        }
    }
}

// ---------------------------------------------------------------------------
extern "C" void kernel_launch(void* const* d_in, const int* in_sizes, int n_in,
                              void* d_out, int out_size, void* d_ws, size_t ws_size,
                              hipStream_t stream)
{
    const float* x   = (const float*)d_in[0];
    const float* tmv = (const float*)d_in[1];
    const float* w1v = (const float*)d_in[2];
    const float* b1v = (const float*)d_in[3];
    const float* w2v = (const float*)d_in[4];
    const float* w1t = (const float*)d_in[5];
    const float* b1t = (const float*)d_in[6];
    const float* w2t = (const float*)d_in[7];
    const float* wx  = (const float*)d_in[8];
    const float* bx  = (const float*)d_in[9];
    const float* wt  = (const float*)d_in[10];
    const float* bt  = (const float*)d_in[11];
    float* out = (float*)d_out;

    // ws: [0,1MB) BmatT bf16 [512][1024]  (Hc eliminated — fused into gemm)
    unsigned short* Bws = (unsigned short*)d_ws;

    combine_kernel<<<256, 256, 0, stream>>>(w2v, w2t, wx, wt, Bws);
    gemm_fused_kernel<<<dim3(MM / 128, PP / 128), 256, 0, stream>>>(
        x, tmv, w1v, b1v, w1t, b1t, Bws, bx, bt, out);
}

// Round 4
// 125.580 us; speedup vs baseline: 1.1285x; 1.1285x over previous
//
#include <hip/hip_runtime.h>
#include <cstdint>
#include <cstddef>

// Problem constants
#define FF 64
#define EE 64
#define HH 8
#define PP 512
#define MM 16384   // B*T = 64*256
#define KK 1024    // 2 * F * H  (both branches concatenated)

typedef __bf16 bf16x8 __attribute__((ext_vector_type(8)));
typedef float  floatx4 __attribute__((ext_vector_type(4)));

// float -> bf16 (RNE)
__device__ __forceinline__ unsigned short f2bf(float f) {
    unsigned int u = __float_as_uint(f);
    u += 0x7FFFu + ((u >> 16) & 1u);
    return (unsigned short)(u >> 16);
}

__device__ __forceinline__ unsigned pack2(unsigned short a, unsigned short b) {
    return (unsigned)a | ((unsigned)b << 16);
}

// tanh from pre-scaled arg t = (val*w+b)*2*log2e:  1 - 2/(exp2(t)+1)
// (the 2*log2e factor is folded into the LDS-staged w1/b1)
__device__ __forceinline__ float fast_tanh_s(float t) {
    float e, r;
    asm("v_exp_f32 %0, %1" : "=v"(e) : "v"(t));
    float d = e + 1.0f;
    asm("v_rcp_f32 %0, %1" : "=v"(r) : "v"(d));
    return __builtin_fmaf(-2.0f, r, 1.0f);
}

// async global->LDS, 16B per lane; LDS dest = wave-uniform base + lane*16
__device__ __forceinline__ void gl_lds16(const unsigned short* g, unsigned short* s) {
    __builtin_amdgcn_global_load_lds(
        (__attribute__((address_space(1))) void*)(void*)g,
        (__attribute__((address_space(3))) void*)s,
        16, 0, 0);
}

// ---------------------------------------------------------------------------
// Phase 1: BmatT[n][k] (bf16, k-contiguous), k = br*512 + f*8 + h
//   BmatT[n][br,f,h] = sum_e w2[f,h,e] * W[(f*64+e)*512 + n]
// ---------------------------------------------------------------------------
__global__ __launch_bounds__(256) void combine_kernel(
    const float* __restrict__ w2v, const float* __restrict__ w2t,
    const float* __restrict__ wx,  const float* __restrict__ wt,
    unsigned short* __restrict__ BmatT)
{
    const int tid = threadIdx.x;
    const int bid = blockIdx.x;
    const int br = bid >> 7;
    const int f  = (bid >> 1) & 63;
    const int nh = bid & 1;
    const float* __restrict__ w2 = br ? w2t : w2v;   // [F][H][E]
    const float* __restrict__ W  = br ? wt  : wx;    // [F*E][P]
    __shared__ float w2s[HH * EE];
    for (int i = tid; i < HH * EE; i += 256) w2s[i] = w2[f * HH * EE + i];
    __syncthreads();
    const int n = nh * 256 + tid;
    float acc[HH] = {0,0,0,0,0,0,0,0};
    const float* Wcol = W + (size_t)f * EE * PP + n;
    #pragma unroll 8
    for (int e = 0; e < EE; ++e) {
        const float wv = Wcol[(size_t)e * PP];
        #pragma unroll
        for (int h = 0; h < HH; ++h)
            acc[h] = __builtin_fmaf(w2s[h * EE + e], wv, acc[h]);
    }
    uint4 v;
    v.x = pack2(f2bf(acc[0]), f2bf(acc[1]));
    v.y = pack2(f2bf(acc[2]), f2bf(acc[3]));
    v.z = pack2(f2bf(acc[4]), f2bf(acc[5]));
    v.w = pack2(f2bf(acc[6]), f2bf(acc[7]));
    *reinterpret_cast<uint4*>(&BmatT[(size_t)n * KK + br * 512 + f * 8]) = v;
}

// ---------------------------------------------------------------------------
// Phase 2: fused featurize + GEMM, restructured to cut tanh redundancy.
//   out[m][n] = sum_k A[m][k]*BmatT[n][k] + bx[n] + bt[n]
//   A[m][br*512+f*8+h] = tanh(in_br[m][f]*w1[f][h]+b1[f][h])  in-tile.
// 512 threads (8 waves), tile 64m x 256n, BK=64.
//   - n-tiles = 2 -> tanh redundancy 2x (was 4x); per k0-iter each thread
//     computes exactly ONE 8-tanh chunk (was 4) -> VALU per iter ~180cy vs
//     MFMA 78cy, overlapped across 2 co-resident blocks (16 waves/CU).
//   - wave grid 2m x 4n; acc 2x4 of 16x16 -> 32 VGPR accumulator.
//   - LDS: As 8KB + Bs 32KB + w1s/b1s 8KB = 48KB -> 2 blocks/CU.
//   - XOR-swizzle (chunk c at physical c^(row&7)) on both As and Bs.
//   - grid (256,2): the 2 n-tiles of an m-stripe are ids x, x+256 == x mod 8
//     -> same XCD -> x/time L2 reuse.
//   - epilogue: nt innermost -> 4x64B contiguous per row -> full-line writes.
// ---------------------------------------------------------------------------
__global__ __launch_bounds__(512, 4) void gemm_fused_kernel(
    const float* __restrict__ x,   const float* __restrict__ tmv,
    const float* __restrict__ w1v, const float* __restrict__ b1v,
    const float* __restrict__ w1t, const float* __restrict__ b1t,
    const unsigned short* __restrict__ Bt,  // BmatT [PP][KK]
    const float* __restrict__ bx, const float* __restrict__ bt,
    float* __restrict__ out)                 // [MM][PP]
{
    __shared__ __align__(16) unsigned short As[64 * 64];    // 8 KB
    __shared__ __align__(16) unsigned short Bs[256 * 64];   // 32 KB
    __shared__ __align__(16) float w1s[2 * FF * HH];        // 4 KB (pre-scaled)
    __shared__ __align__(16) float b1s[2 * FF * HH];        // 4 KB (pre-scaled)

    const int tid  = threadIdx.x;
    const int wave = tid >> 6;
    const int lane = tid & 63;
    const int m0 = blockIdx.x * 64;
    const int n0 = blockIdx.y * 256;

    // stage w1/b1 scaled by 2*log2e (folds the mul out of every tanh)
    {
        const float c = 2.8853900817779268f;
        #pragma unroll
        for (int t = 0; t < 2; ++t) {
            const int idx = tid + t * 512;
            const int br  = idx >> 9;
            const int rem = idx & 511;
            w1s[idx] = (br ? w1t : w1v)[rem] * c;
            b1s[idx] = (br ? b1t : b1v)[rem] * c;
        }
    }
    __syncthreads();

    const int wm  = wave >> 2;             // 0..1  (m quadrant, 32 rows)
    const int wn  = wave & 3;              // 0..3  (n quadrant, 64 cols)
    const int q   = lane >> 4;
    const int ml  = lane & 15;
    const int mlx = ml & 7;
    const int lr  = lane >> 3;             // 0..7 row within 8-row segment
    const int lkg = ((lane & 7) ^ lr) * 8; // swizzled global k-offset (shorts)
    const int fi  = tid & 7;               // feature sub-index for A-compute
    const int arow = tid >> 3;             // 0..63: A row this thread computes
    const int pchunk = (fi ^ (arow & 7)) * 8;

    floatx4 acc[2][4];
    #pragma unroll
    for (int i = 0; i < 2; ++i)
        #pragma unroll
        for (int j = 0; j < 4; ++j)
            acc[i][j] = (floatx4){0.f, 0.f, 0.f, 0.f};

    for (int k0 = 0; k0 < KK; k0 += 64) {
        const int br = k0 >> 9;
        const int f0 = (k0 >> 3) & 63;

        // ---- B staging (DMA overlaps the tanh VALU below) ----
        #pragma unroll
        for (int i = 0; i < 4; ++i) {
            const int seg = wave * 4 + i;        // 0..31
            gl_lds16(&Bt[(size_t)(n0 + seg * 8 + lr) * KK + k0 + lkg], &Bs[seg * 512]);
        }

        // ---- A tile: one (row, f) chunk of 8 tanh per thread ----
        {
            const float* __restrict__ inp = br ? tmv : x;
            const int f = f0 + fi;
            const float val = inp[(size_t)(m0 + arow) * FF + f];
            const float4 wlo = reinterpret_cast<const float4*>(w1s)[br * 128 + f * 2];
            const float4 whi = reinterpret_cast<const float4*>(w1s)[br * 128 + f * 2 + 1];
            const float4 blo = reinterpret_cast<const float4*>(b1s)[br * 128 + f * 2];
            const float4 bhi = reinterpret_cast<const float4*>(b1s)[br * 128 + f * 2 + 1];
            float hv[8];
            hv[0] = fast_tanh_s(__builtin_fmaf(val, wlo.x, blo.x));
            hv[1] = fast_tanh_s(__builtin_fmaf(val, wlo.y, blo.y));
            hv[2] = fast_tanh_s(__builtin_fmaf(val, wlo.z, blo.z));
            hv[3] = fast_tanh_s(__builtin_fmaf(val, wlo.w, blo.w));
            hv[4] = fast_tanh_s(__builtin_fmaf(val, whi.x, bhi.x));
            hv[5] = fast_tanh_s(__builtin_fmaf(val, whi.y, bhi.y));
            hv[6] = fast_tanh_s(__builtin_fmaf(val, whi.z, bhi.z));
            hv[7] = fast_tanh_s(__builtin_fmaf(val, whi.w, bhi.w));
            uint4 v;
            v.x = pack2(f2bf(hv[0]), f2bf(hv[1]));
            v.y = pack2(f2bf(hv[2]), f2bf(hv[3]));
            v.z = pack2(f2bf(hv[4]), f2bf(hv[5]));
            v.w = pack2(f2bf(hv[6]), f2bf(hv[7]));
            *reinterpret_cast<uint4*>(&As[arow * 64 + pchunk]) = v;
        }
        __syncthreads();   // As writes + Bs DMA visible

        #pragma unroll
        for (int kk = 0; kk < 64; kk += 32) {
            const int cl = (kk >> 3) + q;          // logical chunk 0..7
            const int co = (cl ^ mlx) * 8;          // swizzled offset (shorts)
            bf16x8 af[2], bfr[4];
            #pragma unroll
            for (int mt = 0; mt < 2; ++mt)
                af[mt] = *reinterpret_cast<const bf16x8*>(
                    &As[(wm * 32 + mt * 16 + ml) * 64 + co]);
            #pragma unroll
            for (int nt = 0; nt < 4; ++nt)
                bfr[nt] = *reinterpret_cast<const bf16x8*>(
                    &Bs[(wn * 64 + nt * 16 + ml) * 64 + co]);
            #pragma unroll
            for (int mt = 0; mt < 2; ++mt)
                #pragma unroll
                for (int nt = 0; nt < 4; ++nt)
                    acc[mt][nt] = __builtin_amdgcn_mfma_f32_16x16x32_bf16(
                        af[mt], bfr[nt], acc[mt][nt], 0, 0, 0);
        }
        __syncthreads();   // before next iteration overwrites LDS
    }

    // epilogue: nt innermost -> 4 consecutive 64B chunks per output row
    float bias[4];
    #pragma unroll
    for (int nt = 0; nt < 4; ++nt) {
        const int n = n0 + wn * 64 + nt * 16 + ml;
        bias[nt] = bx[n] + bt[n];
    }
    #pragma unroll
    for (int mt = 0; mt < 2; ++mt) {
        const int mb = m0 + wm * 32 + mt * 16 + q * 4;
        #pragma unroll
        for (int r = 0; r < 4; ++r) {
            float* orow = out + (size_t)(mb + r) * PP + n0 + wn * 64 + ml;
            #pragma unroll
            for (int nt = 0; nt < 4; ++nt)
                orow[nt * 16] = acc[mt][nt][r] + bias[nt];
        }
    }
}

// ---------------------------------------------------------------------------
extern "C" void kernel_launch(void* const* d_in, const int* in_sizes, int n_in,
                              void* d_out, int out_size, void* d_ws, size_t ws_size,
                              hipStream_t stream)
{
    const float* x   = (const float*)d_in[0];
    const float* tmv = (const float*)d_in[1];
    const float* w1v = (const float*)d_in[2];
    const float* b1v = (const float*)d_in[3];
    const float* w2v = (const float*)d_in[4];
    const float* w1t = (const float*)d_in[5];
    const float* b1t = (const float*)d_in[6];
    const float* w2t = (const float*)d_in[7];
    const float* wx  = (const float*)d_in[8];
    const float* bx  = (const float*)d_in[9];
    const float* wt  = (const float*)d_in[10];
    const float* bt  = (const float*)d_in[11];
    float* out = (float*)d_out;

    // ws: [0,1MB) BmatT bf16 [512][1024]
    unsigned short* Bws = (unsigned short*)d_ws;

    combine_kernel<<<256, 256, 0, stream>>>(w2v, w2t, wx, wt, Bws);
    gemm_fused_kernel<<<dim3(MM / 64, PP / 256), 512, 0, stream>>>(
        x, tmv, w1v, b1v, w1t, b1t, Bws, bx, bt, out);
}